// Round 7
// baseline (127.110 us; speedup 1.0000x reference)
//
#include <hip/hip_runtime.h>
#include <hip/hip_bf16.h>

// FC_KANLayer: B=6, T=1024, D_IN=256, D_OUT=512, NUM_GRIDS=8
// FUNC_LIST = [rbf, bs, dog, base, rbf, bs]
// f32 in/out; GEMMs via bf16 MFMA.
// R19: zero-LDS direct-to-register GEMM. R18 counters proved the spline GEMM
// ran all 49us at 1840 cy/iter: the 2-buf loop's vmcnt(0)-before-issue is
// structurally serial on memory latency. MFMA fragments for this tile are
// per-lane short8s at (row)*KS + k + q*8 -> load them straight from global
// (immediate k-offsets, 8 row-base pointers), no LDS / barriers / waitcnt asm.
// Compiler software-pipelines the unrolled loop; GEMM waves (VMEM+MFMA pipes)
// interleave freely with DoG waves (VALU+trans pipes) at high occupancy.

typedef short short8 __attribute__((ext_vector_type(8)));
typedef float floatx4 __attribute__((ext_vector_type(4)));

using bf16 = __hip_bfloat16;

#define LOG2E 1.44269504088896340736f
// c = sqrt(0.5*log2(e)); exp(-0.5 x^2) = exp2(-(c x)^2)
#define DOG_C  0.84932180028801904f
#define DOG_IC 1.17741002251547466f   // 1/c

constexpr int Tn   = 1024;
constexpr int DIN  = 256;
constexpr int DOUT = 512;
constexpr int NG   = 8;
constexpr int KSP  = DIN * NG;            // 2048
constexpr float INV_DENOM = 7.0f / 3.0f;  // 1/DENOM, DENOM = 3/7

__device__ __forceinline__ unsigned int bf16bits(float v) {
    return (unsigned int)__builtin_bit_cast(unsigned short, __float2bfloat16(v));
}
__device__ __forceinline__ float frombits(unsigned int u) {
    return __builtin_bit_cast(float, u);
}

// ================= K1 ========================================================
// [0,1536): LN+basis wave-per-row | [1536,2112): f32->bf16 convert (x8 vec)
// [2112,2176): dog-param pack into [DIN/8][DOUT][8] (pre-scaled by DOG_C)
__global__ __launch_bounds__(256) void k1_kernel(
        const float* __restrict__ X,
        const float* __restrict__ w,
        const float* __restrict__ b,
        const float* __restrict__ grid_rbf,
        const float* __restrict__ grid_bs,
        const float* __restrict__ sw,
        const float* __restrict__ bw,
        const float* __restrict__ sc,
        const float* __restrict__ tr,
        bf16* __restrict__ Amat,            // [4096][2048]
        bf16* __restrict__ Sm,              // [1024][256]
        float* __restrict__ Xn2,            // [1024][256]
        bf16* __restrict__ swb,             // [512][2048]
        bf16* __restrict__ bwb,             // [512][256]
        unsigned int* __restrict__ roP,     // [32][512][8] packed bf16 (c/s, -c*t/s)
        unsigned short* __restrict__ wnP) { // [32][512][8] bf16 (-bw/c)
    int tid = threadIdx.x, bid = blockIdx.x;

    if (bid >= 2112) {
        // ---- pack role: one thread per (dblk, dout) ------------------------
        int task = (bid - 2112) * 256 + tid;     // [0, 16384)
        int dout = task & 511, dblk = task >> 9; // dblk in [0,32)
        int base = dout * DIN + dblk * 8;
        float4 s0 = *(const float4*)&sc[base];
        float4 s1 = *(const float4*)&sc[base + 4];
        float4 t0v = *(const float4*)&tr[base];
        float4 t1v = *(const float4*)&tr[base + 4];
        float4 b0v = *(const float4*)&bw[base];
        float4 b1v = *(const float4*)&bw[base + 4];
        float vs[8] = {s0.x, s0.y, s0.z, s0.w, s1.x, s1.y, s1.z, s1.w};
        float vt[8] = {t0v.x, t0v.y, t0v.z, t0v.w, t1v.x, t1v.y, t1v.z, t1v.w};
        float vb[8] = {b0v.x, b0v.y, b0v.z, b0v.w, b1v.x, b1v.y, b1v.z, b1v.w};
        unsigned int ro_[8];
        unsigned short wn_[8];
        #pragma unroll
        for (int k = 0; k < 8; k++) {
            float inv = DOG_C / vs[k];
            ro_[k] = bf16bits(inv) | (bf16bits(-vt[k] * inv) << 16);
            wn_[k] = (unsigned short)bf16bits(-vb[k] * DOG_IC);
        }
        size_t obase = ((size_t)dblk * 512 + dout) * 8;
        uint4 r0; r0.x = ro_[0]; r0.y = ro_[1]; r0.z = ro_[2]; r0.w = ro_[3];
        uint4 r1; r1.x = ro_[4]; r1.y = ro_[5]; r1.z = ro_[6]; r1.w = ro_[7];
        *(uint4*)&roP[obase]     = r0;
        *(uint4*)&roP[obase + 4] = r1;
        uint4 wv_;
        wv_.x = (unsigned int)wn_[0] | ((unsigned int)wn_[1] << 16);
        wv_.y = (unsigned int)wn_[2] | ((unsigned int)wn_[3] << 16);
        wv_.z = (unsigned int)wn_[4] | ((unsigned int)wn_[5] << 16);
        wv_.w = (unsigned int)wn_[6] | ((unsigned int)wn_[7] << 16);
        *(uint4*)&wnP[obase] = wv_;
        return;
    }
    if (bid >= 1536) {
        // ---- convert role ---------------------------------------------------
        int e = ((bid - 1536) * 256 + tid) * 8;    // [0, 1179648)
        const float* src = (e < 1048576) ? (sw + e) : (bw + (e - 1048576));
        bf16* dst = (e < 1048576) ? (swb + e) : (bwb + (e - 1048576));
        float4 v0 = *(const float4*)src;
        float4 v1 = *(const float4*)(src + 4);
        short8 p;
        p[0] = __builtin_bit_cast(short, __float2bfloat16(v0.x));
        p[1] = __builtin_bit_cast(short, __float2bfloat16(v0.y));
        p[2] = __builtin_bit_cast(short, __float2bfloat16(v0.z));
        p[3] = __builtin_bit_cast(short, __float2bfloat16(v0.w));
        p[4] = __builtin_bit_cast(short, __float2bfloat16(v1.x));
        p[5] = __builtin_bit_cast(short, __float2bfloat16(v1.y));
        p[6] = __builtin_bit_cast(short, __float2bfloat16(v1.z));
        p[7] = __builtin_bit_cast(short, __float2bfloat16(v1.w));
        *(short8*)dst = p;
        return;
    }

    // ---- LN + basis role ----------------------------------------------------
    int wv = tid >> 6, lane = tid & 63;
    int row = bid * 4 + wv;              // b*1024 + t
    int batch = row >> 10, t = row & 1023;

    float x[4];
    #pragma unroll
    for (int j = 0; j < 4; j++) x[j] = X[(size_t)row * DIN + j * 64 + lane];
    float s = x[0] + x[1] + x[2] + x[3];
    float ss = x[0] * x[0] + x[1] * x[1] + x[2] * x[2] + x[3] * x[3];
    #pragma unroll
    for (int o = 1; o < 64; o <<= 1) {
        s  += __shfl_xor(s, o);
        ss += __shfl_xor(ss, o);
    }
    float mu = s * (1.0f / DIN);
    float rstd = rsqrtf(ss * (1.0f / DIN) - mu * mu + 1e-5f);

    float xn[4];
    #pragma unroll
    for (int j = 0; j < 4; j++) {
        int din = j * 64 + lane;
        xn[j] = (x[j] - mu) * rstd * w[din] + b[din];
    }

    if (batch == 2) {
        #pragma unroll
        for (int j = 0; j < 4; j++)
            Xn2[(size_t)t * DIN + j * 64 + lane] = xn[j];
    } else if (batch == 3) {
        #pragma unroll
        for (int j = 0; j < 4; j++) {
            float e = __builtin_amdgcn_exp2f(-xn[j] * LOG2E);
            float si = xn[j] * __builtin_amdgcn_rcpf(1.0f + e);
            Sm[(size_t)t * DIN + j * 64 + lane] = __float2bfloat16(si);
        }
    } else {
        int which = (batch == 0) ? 0 : (batch == 1) ? 1 : (batch == 4) ? 2 : 3;
        bool is_rbf = (batch == 0) || (batch == 4);
        #pragma unroll
        for (int j = 0; j < 4; j++) {
            float v = xn[j];
            float outv[NG];
            if (is_rbf) {
                #pragma unroll
                for (int g = 0; g < NG; g++) {
                    float d = (v - grid_rbf[g]) * INV_DENOM;
                    outv[g] = __builtin_amdgcn_exp2f(-d * d * LOG2E);
                }
            } else {
                float g[12];
                #pragma unroll
                for (int i = 0; i < 12; i++) g[i] = grid_bs[i];
                float ih = 1.0f / (g[1] - g[0]);
                float ihk[3] = {ih, ih * 0.5f, ih * (1.0f / 3.0f)};
                float bs_[11];
                #pragma unroll
                for (int i = 0; i < 11; i++)
                    bs_[i] = (v >= g[i] && v < g[i + 1]) ? 1.0f : 0.0f;
                #pragma unroll
                for (int k = 1; k <= 3; k++) {
                    float rk = ihk[k - 1];
                    #pragma unroll
                    for (int i = 0; i < 10; i++) {
                        if (i <= 10 - k) {
                            bs_[i] = (v - g[i]) * rk * bs_[i]
                                   + (g[i + k + 1] - v) * rk * bs_[i + 1];
                        }
                    }
                }
                #pragma unroll
                for (int gg = 0; gg < NG; gg++) outv[gg] = bs_[gg];
            }
            short8 pv;
            #pragma unroll
            for (int gg = 0; gg < NG; gg++)
                pv[gg] = __builtin_bit_cast(short, __float2bfloat16(outv[gg]));
            *(short8*)((short*)Amat + (size_t)(which * Tn + t) * KSP
                       + (size_t)(j * 64 + lane) * NG) = pv;
        }
    }
}

// ---------------- GEMM core: 128x64 tile, 2 waves, direct-to-register --------
// Wave wv owns rows [wv*64, wv*64+64) x all 64 cols: 4x4 16x16 frags.
// A fragment for lane (m,q), frag r:  A[(row0+wv*64+r*16+m)*KS + k + q*8..+7]
// B fragment:                        B[(col0+     r*16+m)*KS + k + q*8..+7]
// -> plain short8 global loads, k-offset is an immediate (<=4032 B for
// KS=2048, iters=64). No LDS, no barriers, no waitcnt asm: the compiler
// pipelines the unrolled loop with many outstanding loads.
template <int KS>
__device__ __forceinline__ void gemm_direct(const short* __restrict__ A,
                                            const short* __restrict__ Bw,
                                            int row0, int col0, int iters,
                                            int tid, floatx4 acc[4][4]) {
    int wv = tid >> 6, lane = tid & 63;
    int m = lane & 15, q = lane >> 4;
    const short* pa[4];
    const short* pb[4];
    #pragma unroll
    for (int r = 0; r < 4; r++) {
        pa[r] = A  + (size_t)(row0 + wv * 64 + r * 16 + m) * KS + q * 8;
        pb[r] = Bw + (size_t)(col0 +           r * 16 + m) * KS + q * 8;
    }
    // outer loop of 8-iter chunks: bounded scheduling window, pointer bump
    for (int o = 0; o < iters; o += 8) {
        #pragma unroll
        for (int i = 0; i < 8; i++) {
            short8 a[4], b[4];
            #pragma unroll
            for (int r = 0; r < 4; r++) {
                a[r] = *(const short8*)(pa[r] + i * 32);
                b[r] = *(const short8*)(pb[r] + i * 32);
            }
            __builtin_amdgcn_s_setprio(1);
            #pragma unroll
            for (int r = 0; r < 4; r++)
                #pragma unroll
                for (int c = 0; c < 4; c++)
                    acc[r][c] = __builtin_amdgcn_mfma_f32_16x16x32_bf16(
                        a[r], b[c], acc[r][c], 0, 0, 0);
            __builtin_amdgcn_s_setprio(0);
        }
        #pragma unroll
        for (int r = 0; r < 4; r++) { pa[r] += 256; pb[r] += 256; }
    }
}

// ================= K2: merged heterogeneous kernel (128-thr, ZERO LDS) =======
// [0,256):    spline GEMM 128x64, K=2048; bid = nt*32+mt so the 8 nt-tiles of
//             one A-panel all land on XCD (mt%8) -> A fetched once per L2.
// [256,320):  base GEMM 128x64, K=256
// [320,1344): DoG: 128 dout x 4 t
__global__ __launch_bounds__(128) void k2_kernel(const bf16* __restrict__ Amat,
                                                 const bf16* __restrict__ SWb,
                                                 const bf16* __restrict__ Sm,
                                                 const bf16* __restrict__ BWb,
                                                 const float* __restrict__ Xn2,
                                                 const unsigned int* __restrict__ roP,
                                                 const unsigned short* __restrict__ wnP,
                                                 float* __restrict__ out) {
    int bid = blockIdx.x, tid = threadIdx.x;

    if (bid < 320) {
        // ---- GEMM roles ----------------------------------------------------
        bool spline = bid < 256;
        int mt, nt;
        if (spline) { int idx = bid;        mt = idx & 31; nt = idx >> 5; }
        else        { int idx = bid - 256;  mt = idx & 7;  nt = idx >> 3; }
        int row0 = mt * 128, col0 = nt * 64;
        floatx4 acc[4][4];
        #pragma unroll
        for (int r = 0; r < 4; r++)
            #pragma unroll
            for (int c = 0; c < 4; c++) acc[r][c] = (floatx4)(0.0f);

        if (spline) {
            gemm_direct<KSP>((const short*)Amat, (const short*)SWb,
                             row0, col0, 64, tid, acc);
        } else {
            gemm_direct<DIN>((const short*)Sm, (const short*)BWb,
                             row0, col0, 8, tid, acc);
        }

        int wv = tid >> 6, lane = tid & 63;
        int m = lane & 15, q = lane >> 4;
        size_t rowbase;
        if (spline) {
            int which = row0 >> 10;              // 128-row tile within one batch
            int batch = (which == 0) ? 0 : (which == 1) ? 1 : (which == 2) ? 4 : 5;
            rowbase = (size_t)batch * Tn + (row0 & 1023);
        } else {
            rowbase = (size_t)3 * Tn + row0;
        }
        #pragma unroll
        for (int r = 0; r < 4; r++)
            #pragma unroll
            for (int c = 0; c < 4; c++)
                #pragma unroll
                for (int rr = 0; rr < 4; rr++) {
                    int rloc = wv * 64 + r * 16 + q * 4 + rr;
                    int col = col0 + c * 16 + m;
                    out[(rowbase + rloc) * DOUT + col] = acc[r][c][rr];
                }
    } else {
        // ---- DoG role: 128 dout x 4 t --------------------------------------
        int db = bid - 320;                      // [0,1024)
        int dt = db & 3, t0 = (db >> 2) * 4;     // t0 in {0,4,...,1020}
        int dout = dt * 128 + tid;

        const unsigned int*   rop = roP + (size_t)dout * 8;
        const unsigned short* wnp = wnP + (size_t)dout * 8;
        const float* xrow[4];
        #pragma unroll
        for (int j = 0; j < 4; j++) xrow[j] = Xn2 + (size_t)(t0 + j) * DIN;

        float acc[4] = {0.f, 0.f, 0.f, 0.f};

        // prefetch first param block
        uint4 ra = *(const uint4*)rop;
        uint4 rb = *(const uint4*)(rop + 4);
        uint4 wq = *(const uint4*)wnp;

        for (int db8 = 0; db8 < 32; db8++) {
            int d = db8 * 8;
            uint4 ca = ra, cb = rb, cw = wq;
            if (db8 < 31) {
                rop += 4096;   // 512*8 uints per d-block
                wnp += 4096;   // 512*8 ushorts per d-block
                ra = *(const uint4*)rop;
                rb = *(const uint4*)(rop + 4);
                wq = *(const uint4*)wnp;
            }
            unsigned int roarr[8] = {ca.x, ca.y, ca.z, ca.w,
                                     cb.x, cb.y, cb.z, cb.w};
            unsigned int wword[4] = {cw.x, cw.y, cw.z, cw.w};
            #pragma unroll
            for (int g = 0; g < 2; g++) {
                float4 xj[4];
                #pragma unroll
                for (int j = 0; j < 4; j++)
                    xj[j] = *(const float4*)&xrow[j][d + g * 4];   // uniform
                #pragma unroll
                for (int kq = 0; kq < 4; kq++) {
                    int k = g * 4 + kq;
                    unsigned int rw = roarr[k];
                    float r = frombits(rw << 16);
                    float o = frombits(rw & 0xFFFF0000u);
                    unsigned int ww = wword[k >> 1];
                    float w = (k & 1) ? frombits(ww & 0xFFFF0000u)
                                      : frombits(ww << 16);
                    #pragma unroll
                    for (int j = 0; j < 4; j++) {
                        float xval = ((const float*)&xj[j])[kq];
                        float z = fmaf(xval, r, o);
                        float e = __builtin_amdgcn_exp2f(-(z * z));
                        acc[j] = fmaf(z * e, w, acc[j]);
                    }
                }
            }
        }
        size_t base = (size_t)2 * Tn * DOUT + (size_t)t0 * DOUT + dout;
        #pragma unroll
        for (int j = 0; j < 4; j++) out[base + (size_t)j * DOUT] = acc[j];
    }
}

extern "C" void kernel_launch(void* const* d_in, const int* in_sizes, int n_in,
                              void* d_out, int out_size, void* d_ws, size_t ws_size,
                              hipStream_t stream) {
    const float* X        = (const float*)d_in[0];
    const float* ln_w     = (const float*)d_in[1];
    const float* ln_b     = (const float*)d_in[2];
    const float* base_w   = (const float*)d_in[3];
    const float* spline_w = (const float*)d_in[4];
    const float* scale    = (const float*)d_in[5];
    const float* transl   = (const float*)d_in[6];
    const float* grid_rbf = (const float*)d_in[7];
    const float* grid_bs  = (const float*)d_in[8];
    float* out = (float*)d_out;

    char* ws = (char*)d_ws;
    bf16*  Amat = (bf16*)ws;                                   // 16 MiB   [4096][2048]
    bf16*  SWb  = (bf16*)(ws + 16777216);                      // 2 MiB    [512][2048]
    bf16*  BWb  = (bf16*)(ws + 18874368);                      // 0.25 MiB [512][256]
    bf16*  Sm   = (bf16*)(ws + 19136512);                      // 0.5 MiB  [1024][256]
    float* Xn2  = (float*)(ws + 19660800);                     // 1 MiB    [1024][256]
    unsigned int*   roP = (unsigned int*)(ws + 20709376);      // 0.5 MiB  [32][512][8]
    unsigned short* wnP = (unsigned short*)(ws + 21233664);    // 0.25 MiB [32][512][8]

    k1_kernel<<<2176, 256, 0, stream>>>(X, ln_w, ln_b, grid_rbf, grid_bs,
                                        spline_w, base_w, scale, transl,
                                        Amat, Sm, Xn2, SWb, BWb, roP, wnP);
    k2_kernel<<<1344, 128, 0, stream>>>(Amat, SWb, Sm, BWb, Xn2, roP, wnP, out);
}